// Round 13
// baseline (1161.692 us; speedup 1.0000x reference)
//
#include <hip/hip_runtime.h>
#include <hip/hip_bf16.h>
#include <math.h>

#define H 450
#define HP 464            // padded A row stride (bf16 elems; 16B-aligned rows)
#define KP 480            // padded K extent: 15 MFMA chunks of 32
#define LAT 56
#define V 780
#define LW 24
#define NE 46
#define NF 23
#define SLOT (1024*HP)
#define SROWS 2048
#define QROWS (24*1024)
#define PROWS (47*1024)
#define PTGT  (23*1024)
#define QBLK 6144
#define XBSZ ((size_t)QROWS * H)      // one X block, elems (H stride — r16 layout)
#define BTROWS 5312                   // packed B^T rows
#define EXB (256 * 16 * 256)          // exchange buffer elems (bf16)

// prep_all fused ranges
#define PR0 1856                      // bias4 pack (+ out zero in first 4)
#define PRF (PR0 + 512)               // flagM/flagR zero
#define PR1 (PRF + PROWS)             // pl zero
#define PR2 (PR1 + BTROWS * KP)       // prep_w
#define PR3 (PR2 + 24 * 1024 * 225)   // gather_x
#define PR4 (PR3 + 2 * 1024 * H)      // tv gemm (Qtv z=0 / Ptv z=1)

// post_scan fused ranges
#define HVR (22 * (SLOT / 8))         // hv_fixup (short8 units)
#define QRR (HVR + 1024 * H)          // q_root

typedef __hip_bfloat16 bf16;
typedef __attribute__((ext_vector_type(8))) short short8;
typedef __attribute__((ext_vector_type(4))) short short4v;
typedef __attribute__((ext_vector_type(4))) float f32x4;

#define MFMA16(a,b,c) __builtin_amdgcn_mfma_f32_16x16x32_bf16(a,b,c,0,0,0)

__device__ __forceinline__ float sigm_f(float x) { return 1.f / (1.f + __expf(-x)); }
__device__ __forceinline__ float tanh_f(float x) { return 2.f / (1.f + __expf(-2.f * x)) - 1.f; }
__device__ __forceinline__ float toF(bf16 x) { return __bfloat162float(x); }
__device__ __forceinline__ float bf2f(short s) {
    unsigned u = ((unsigned)(unsigned short)s) << 16;
    return __uint_as_float(u);
}
__device__ __forceinline__ short f2bs(float f) {
    bf16 t = __float2bfloat16(f);
    return *reinterpret_cast<short*>(&t);
}
__device__ __forceinline__ void stV(float* p, float v) { *p = v; }
__device__ __forceinline__ void stV(bf16* p, float v) { *p = __float2bfloat16(v); }
__device__ __forceinline__ short8 ld8(const bf16* p) { return *reinterpret_cast<const short8*>(p); }

// LDS-only barrier
__device__ __forceinline__ void ldsbar() {
    asm volatile("s_waitcnt lgkmcnt(0)" ::: "memory");
    __builtin_amdgcn_s_barrier();
    asm volatile("" ::: "memory");
}

// async global->LDS (gemm staging — measured-good)
__device__ __forceinline__ void gl_lds(const bf16* g, bf16* l) {
    __builtin_amdgcn_global_load_lds(
        (const __attribute__((address_space(1))) void*)g,
        (__attribute__((address_space(3))) void*)l, 16, 0, 0);
}

// 128-row-tile XCD swizzle
__device__ __forceinline__ void xcd_decode128(int b, int C, int& row0, int& col0) {
    int rres = b & 7;
    int colt = (b >> 3) % C;
    int g    = b / (8 * C);
    row0 = (rres + 8 * g) * 128;
    col0 = colt * 128;
}

// 256-row-tile XCD swizzle (row-tile count must be a multiple of 8)
__device__ __forceinline__ void xcd_decode256(int b, int C, int& row0, int& col0) {
    int rres = b & 7;
    int colt = (b >> 3) % C;
    int g    = b / (8 * C);
    row0 = (rres + 8 * g) * 256;
    col0 = colt * 128;
}

// generalized bijective XCD swizzle (needs nwg % 8 == 0 only)
__device__ __forceinline__ void xcd_decode256g(int b, int nwg, int C,
                                               int& row0, int& col0) {
    int swz = (b & 7) * (nwg >> 3) + (b >> 3);
    row0 = (swz / C) * 256;
    col0 = (swz % C) * 128;
}

// ---------------------------------------------------------------------------
// Fused prep: out-zero + bias4 + flag zero + pl-zero + B^T weight pack +
// emb gather + tv GEMMs (Qtv/Ptv).
__global__ __launch_bounds__(256)
void prep_all(const float* __restrict__ zb, const float* __restrict__ hb,
              const float* __restrict__ rb, float* __restrict__ bias4,
              float* __restrict__ out, float* __restrict__ pl,
              int* __restrict__ flags,
              const float* __restrict__ Wz, const float* __restrict__ Wh,
              const float* __restrict__ Wr, const float* __restrict__ Uw,
              const float* __restrict__ Ww, const float* __restrict__ Wo,
              const float* __restrict__ Ur, bf16* __restrict__ BT,
              const float* __restrict__ emb, const int* __restrict__ wid,
              bf16* __restrict__ x_all,
              const float* __restrict__ tv,
              const float* __restrict__ Wlat, const float* __restrict__ Wbias,
              const float* __restrict__ Ulat, const float* __restrict__ Ubias,
              float* __restrict__ Qtv, float* __restrict__ Ptv) {
    int idx = blockIdx.x * 256 + threadIdx.x;
    if (idx < PR0) {
        if (idx < 4) out[idx] = 0.f;
        float v = 0.f;
        if (idx < 450)       v = zb[idx];
        else if (idx < 900)  v = hb[idx - 450];
        else if (idx < 1350) v = rb[idx - 900];
        bias4[idx] = v;
    } else if (idx < PRF) {
        flags[idx - PR0] = 0;
    } else if (idx < PR1) {
        pl[idx - PRF] = 0.f;
    } else if (idx < PR2) {
        int e = idx - PR1;
        int r = e / KP, k = e - r * KP;
        const float* src; int n; int N = H; int ld = H;
        if (r < 1856) {
            if (r < 450)       { src = Wz; n = r; }
            else if (r < 900)  { src = Wh; n = r - 450; }
            else if (r < 1350) { src = Wr; n = r - 900; }
            else               { src = Uw; n = r - 1350; }
        } else if (r < 2368) { src = Wz + 450 * 450; n = r - 1856; }
        else if (r < 2880)   { src = Wh + 450 * 450; n = r - 2368; }
        else if (r < 3392)   { src = Ur;             n = r - 2880; }
        else if (r < 3904)   { src = Uw + 450 * 450; n = r - 3392; }
        else if (r < 4416)   { src = Ww;             n = r - 3904; }
        else                 { src = Wo; n = r - 4416; N = V; ld = V; }
        float v = (n < N && k < H) ? src[(size_t)k * ld + n] : 0.f;
        BT[e] = __float2bfloat16(v);
    } else if (idx < PR3) {
        int e = idx - PR2;
        int row = e / 225, h2 = e - row * 225;
        int t = row >> 10, n = row & 1023;
        int v = wid[n * LW + t];
        float2 x = ((const float2*)(emb + (size_t)v * H))[h2];
        bf16* dst = x_all + (size_t)row * HP + 2 * h2;
        dst[0] = __float2bfloat16(x.x);
        dst[1] = __float2bfloat16(x.y);
    } else if (idx < PR4) {
        int e = idx - PR3;
        int z = e / (1024 * H);
        int e2 = e - z * (1024 * H);
        int n = e2 / H, c = e2 - n * H;
        const float* W    = z ? Ulat  : Wlat;
        const float* bias = z ? Ubias : Wbias;
        const float* tvn = tv + n * LAT;
        float a = bias[c];
#pragma unroll 8
        for (int k = 0; k < LAT; k++) a += tvn[k] * W[(size_t)k * H + c];
        (z ? Ptv : Qtv)[(size_t)n * H + c] = a;
    }
}

// ---------------------------------------------------------------------------
// LDS-staged GEMM: 128x128 tile
// ---------------------------------------------------------------------------
template<typename TC>
__global__ __launch_bounds__(256)
void gemm128(const bf16* __restrict__ A, int lda,
             const bf16* __restrict__ Bt, int N, int cblk,
             TC* __restrict__ C, int ldc,
             const float* __restrict__ bias,
             const float* __restrict__ addrow, int addld, int relu) {
    __shared__ bf16 As[128 * 32];
    __shared__ bf16 Bs[128 * 32];
    int tid = threadIdx.x;
    int lane = tid & 63, wave = tid >> 6;
    int wx = wave & 1, wy = wave >> 1;
    int lrow = lane & 15, quad = lane >> 4;
    int perm = ((quad + (lrow >> 1)) & 3) * 8;
    int row0, col0;
    xcd_decode128(blockIdx.x, cblk, row0, col0);
    f32x4 acc[4][4] = {};
    for (int k0i = 0; k0i < 15; k0i++) {
        int k0 = k0i * 32;
#pragma unroll
        for (int r = 0; r < 2; r++) {
            int tt = r * 256 + tid;
            int row = tt >> 2, cl = tt & 3;
            int cg = (cl - (row >> 1)) & 3;
            gl_lds(A  + (size_t)(row0 + row) * lda + k0 + cg * 8, As + tt * 8);
            gl_lds(Bt + (size_t)(col0 + row) * KP  + k0 + cg * 8, Bs + tt * 8);
        }
        __syncthreads();
        short8 a[4], b[4];
#pragma unroll
        for (int f = 0; f < 4; f++)
            a[f] = ld8(As + (wy * 64 + f * 16 + lrow) * 32 + perm);
#pragma unroll
        for (int f = 0; f < 4; f++)
            b[f] = ld8(Bs + (wx * 64 + f * 16 + lrow) * 32 + perm);
#pragma unroll
        for (int fi = 0; fi < 4; fi++)
#pragma unroll
            for (int fj = 0; fj < 4; fj++)
                acc[fi][fj] = MFMA16(a[fi], b[fj], acc[fi][fj]);
        __syncthreads();
    }
#pragma unroll
    for (int fi = 0; fi < 4; fi++)
#pragma unroll
        for (int e = 0; e < 4; e++) {
            int r = row0 + wy * 64 + fi * 16 + quad * 4 + e;
#pragma unroll
            for (int fj = 0; fj < 4; fj++) {
                int c = col0 + wx * 64 + fj * 16 + lrow;
                if (c >= N) continue;
                float v = acc[fi][fj][e];
                if (bias) v += bias[c];
                if (addrow) v += addrow[(size_t)(r & 1023) * addld + c];
                if (relu) v = fmaxf(v, 0.f);
                stV(&C[(size_t)r * ldc + c], v);
            }
        }
}

// ---------------------------------------------------------------------------
// 256x128-tile GEMM, 512 threads
// ---------------------------------------------------------------------------
template<typename TC>
__global__ __launch_bounds__(512)
void gemm256(const bf16* __restrict__ A, int lda,
             const bf16* __restrict__ Bt, int N, int cblk,
             TC* __restrict__ C, int ldc,
             const float* __restrict__ bias,
             const float* __restrict__ addrow, int addld, int relu, int gswz) {
    __shared__ bf16 As[256 * 32];
    __shared__ bf16 Bs[128 * 32];
    int tid = threadIdx.x;
    int lane = tid & 63, wave = tid >> 6;
    int wx = wave & 1, wy = wave >> 1;
    int lrow = lane & 15, quad = lane >> 4;
    int perm = ((quad + (lrow >> 1)) & 3) * 8;
    int row0, col0;
    if (gswz) xcd_decode256g(blockIdx.x, gridDim.x, cblk, row0, col0);
    else      xcd_decode256(blockIdx.x, cblk, row0, col0);
    f32x4 acc[4][4] = {};
    for (int k0i = 0; k0i < 15; k0i++) {
        int k0 = k0i * 32;
#pragma unroll
        for (int r = 0; r < 2; r++) {
            int tt = r * 512 + tid;
            int row = tt >> 2, cl = tt & 3;
            int cg = (cl - (row >> 1)) & 3;
            gl_lds(A + (size_t)(row0 + row) * lda + k0 + cg * 8, As + tt * 8);
        }
        {
            int row = tid >> 2, cl = tid & 3;
            int cg = (cl - (row >> 1)) & 3;
            gl_lds(Bt + (size_t)(col0 + row) * KP + k0 + cg * 8, Bs + tid * 8);
        }
        __syncthreads();
        short8 a[4], b[4];
#pragma unroll
        for (int f = 0; f < 4; f++)
            a[f] = ld8(As + (wy * 64 + f * 16 + lrow) * 32 + perm);
#pragma unroll
        for (int f = 0; f < 4; f++)
            b[f] = ld8(Bs + (wx * 64 + f * 16 + lrow) * 32 + perm);
#pragma unroll
        for (int fi = 0; fi < 4; fi++)
#pragma unroll
            for (int fj = 0; fj < 4; fj++)
                acc[fi][fj] = MFMA16(a[fi], b[fj], acc[fi][fj]);
        __syncthreads();
    }
#pragma unroll
    for (int fi = 0; fi < 4; fi++)
#pragma unroll
        for (int e = 0; e < 4; e++) {
            int r = row0 + wy * 64 + fi * 16 + quad * 4 + e;
#pragma unroll
            for (int fj = 0; fj < 4; fj++) {
                int c = col0 + wx * 64 + fj * 16 + lrow;
                if (c >= N) continue;
                float v = acc[fi][fj][e];
                if (bias) v += bias[c];
                if (addrow) v += addrow[(size_t)(r & 1023) * addld + c];
                if (relu) v = fmaxf(v, 0.f);
                stV(&C[(size_t)r * ldc + c], v);
            }
        }
}

// 256-tile fused pre-GEMM: X @ [Wz|Wh|Wr|Ua] (N=1800)
__global__ __launch_bounds__(512)
void gemm256_pre(const bf16* __restrict__ A,
                 const bf16* __restrict__ Bt,
                 bf16* __restrict__ X0,
                 const float* __restrict__ bias4) {
    __shared__ bf16 As[256 * 32];
    __shared__ bf16 Bs[128 * 32];
    int tid = threadIdx.x;
    int lane = tid & 63, wave = tid >> 6;
    int wx = wave & 1, wy = wave >> 1;
    int lrow = lane & 15, quad = lane >> 4;
    int perm = ((quad + (lrow >> 1)) & 3) * 8;
    int row0, col0;
    xcd_decode256(blockIdx.x, 15, row0, col0);
    f32x4 acc[4][4] = {};
    for (int k0i = 0; k0i < 15; k0i++) {
        int k0 = k0i * 32;
#pragma unroll
        for (int r = 0; r < 2; r++) {
            int tt = r * 512 + tid;
            int row = tt >> 2, cl = tt & 3;
            int cg = (cl - (row >> 1)) & 3;
            gl_lds(A + (size_t)(row0 + row) * HP + k0 + cg * 8, As + tt * 8);
        }
        {
            int row = tid >> 2, cl = tid & 3;
            int cg = (cl - (row >> 1)) & 3;
            gl_lds(Bt + (size_t)(col0 + row) * KP + k0 + cg * 8, Bs + tid * 8);
        }
        __syncthreads();
        short8 a[4], b[4];
#pragma unroll
        for (int f = 0; f < 4; f++)
            a[f] = ld8(As + (wy * 64 + f * 16 + lrow) * 32 + perm);
#pragma unroll
        for (int f = 0; f < 4; f++)
            b[f] = ld8(Bs + (wx * 64 + f * 16 + lrow) * 32 + perm);
#pragma unroll
        for (int fi = 0; fi < 4; fi++)
#pragma unroll
            for (int fj = 0; fj < 4; fj++)
                acc[fi][fj] = MFMA16(a[fi], b[fj], acc[fi][fj]);
        __syncthreads();
    }
#pragma unroll
    for (int fi = 0; fi < 4; fi++)
#pragma unroll
        for (int e = 0; e < 4; e++) {
            int r = row0 + wy * 64 + fi * 16 + quad * 4 + e;
#pragma unroll
            for (int fj = 0; fj < 4; fj++) {
                int c = col0 + wx * 64 + fj * 16 + lrow;
                if (c >= 1800) continue;
                int mm = c / 450;
                int cc = c - mm * 450;
                float v = acc[fi][fj][e] + bias4[c];
                X0[(size_t)mm * XBSZ + (size_t)r * H + cc] = __float2bfloat16(v);
            }
        }
}

// p GEMM (256-tile)
__global__ __launch_bounds__(512)
void p_gemm256(const bf16* __restrict__ hs, const bf16* __restrict__ UbT,
               const bf16* __restrict__ XUa, const float* __restrict__ Ptv,
               const float* __restrict__ Us, float* __restrict__ pl) {
    __shared__ bf16 As[256 * 32];
    __shared__ bf16 Bs[128 * 32];
    int tid = threadIdx.x;
    int lane = tid & 63, wave = tid >> 6;
    int wx = wave & 1, wy = wave >> 1;
    int lrow = lane & 15, quad = lane >> 4;
    int perm = ((quad + (lrow >> 1)) & 3) * 8;
    int row0, col0;
    xcd_decode256g(blockIdx.x, 720, 4, row0, col0);
    f32x4 acc[4][4] = {};
    for (int k0i = 0; k0i < 15; k0i++) {
        int k0 = k0i * 32;
#pragma unroll
        for (int r = 0; r < 2; r++) {
            int tt = r * 512 + tid;
            int row = tt >> 2, cl = tt & 3;
            int cg = (cl - (row >> 1)) & 3;
            gl_lds(hs + (size_t)(row0 + row) * HP + k0 + cg * 8, As + tt * 8);
        }
        {
            int row = tid >> 2, cl = tid & 3;
            int cg = (cl - (row >> 1)) & 3;
            gl_lds(UbT + (size_t)(col0 + row) * KP + k0 + cg * 8, Bs + tid * 8);
        }
        __syncthreads();
        short8 a[4], b[4];
#pragma unroll
        for (int f = 0; f < 4; f++)
            a[f] = ld8(As + (wy * 64 + f * 16 + lrow) * 32 + perm);
#pragma unroll
        for (int f = 0; f < 4; f++)
            b[f] = ld8(Bs + (wx * 64 + f * 16 + lrow) * 32 + perm);
#pragma unroll
        for (int fi = 0; fi < 4; fi++)
#pragma unroll
            for (int fj = 0; fj < 4; fj++)
                acc[fi][fj] = MFMA16(a[fi], b[fj], acc[fi][fj]);
        __syncthreads();
    }
#pragma unroll
    for (int fi = 0; fi < 4; fi++)
#pragma unroll
        for (int e = 0; e < 4; e++) {
            int r = row0 + wy * 64 + fi * 16 + quad * 4 + e;
            int t = r >> 10, n = r & 1023;
            int dst = (t < 23) ? (t + 1) : (45 - t);
            float part = 0.f;
#pragma unroll
            for (int fj = 0; fj < 4; fj++) {
                int c = col0 + wx * 64 + fj * 16 + lrow;
                if (c < H) {
                    float h = fmaxf(acc[fi][fj][e] + toF(XUa[((size_t)dst * 1024 + n) * H + c])
                                    + Ptv[(size_t)n * H + c], 0.f);
                    part += h * Us[c];
                }
            }
#pragma unroll
            for (int off = 1; off < 16; off <<= 1)
                part += __shfl_xor(part, off);
            if (lrow == 0) atomicAdd(&pl[1024 + r], part);
        }
}

// ---------------------------------------------------------------------------
// FRAG-SPLIT full scan: 256 blocks x 512 thr (8 waves). Theory: scan was
// per-CU TA-line-throughput bound with only 128 blocks (OccupancyPercent 24%,
// half the CUs idle). Each old 16-wave block is split into a PAIR of 8-wave
// blocks: h=0 owns frags 0-14 (cols 0-239), h=1 owns frags 15-28 (240-449).
// Per-CU line processing halves; all 256 CUs active. Each half needs the
// partner's m/rm columns next phase -> pairwise exchange through L3 via
// agent-scope uint atomics (coherent across XCDs; no L2 flush). All 256
// blocks trivially co-resident (8 waves, 47KB LDS) -> handshake can't
// deadlock. Per-wave compute structure = the frozen r3/r8 pattern (row-major
// panels, compiler-scheduled unrolled k-loops, X prefetch mid-loop).
// ---------------------------------------------------------------------------
__global__ void
__attribute__((amdgpu_flat_work_group_size(512, 512)))
scan_split(bf16* __restrict__ hs,
           const bf16* __restrict__ WzbT, const bf16* __restrict__ WhbT,
           const bf16* __restrict__ UrT,
           const bf16* __restrict__ Xz, const bf16* __restrict__ Xh,
           const bf16* __restrict__ Xr,
           bf16* __restrict__ mex, bf16* __restrict__ rex,
           int* __restrict__ flagM, int* __restrict__ flagR) {
    __shared__ bf16 mnl[2][16][488];
    __shared__ bf16 rml[16][488];
    int tid = threadIdx.x;
    int lane = tid & 63, w = tid >> 6;          // w in [0,8)
    int lrow = lane & 15, quad = lane >> 4;
    int me = blockIdx.x, h = me & 1, p = me >> 1, partner = me ^ 1;
    int row0 = p * 16;
    bool fwd = p < 64;
    int F0 = h ? 15 : 0;
    int nfh = h ? 14 : 15;
    int f0 = F0 + w;
    int f1 = F0 + 8 + w;
    bool hasf1 = (8 + w) < nfh;
    int c0 = f0 * 16 + lrow;                    // <= 367 < H always
    int c1 = f1 * 16 + lrow;
    bool c1ok = hasf1 && (c1 < H);
    int myBase = h ? 240 : 0;
    int myU = (h ? 210 : 240) >> 1;             // own uints per row
    int pBase = h ? 0 : 240;
    int pU = (h ? 240 : 210) >> 1;              // partner uints per row
    unsigned* mexMeU = (unsigned*)(mex + (size_t)me * 16 * 256);
    unsigned* mexPU  = (unsigned*)(mex + (size_t)partner * 16 * 256);
    unsigned* rexMeU = (unsigned*)(rex + (size_t)me * 16 * 256);
    unsigned* rexPU  = (unsigned*)(rex + (size_t)partner * 16 * 256);

    float sreg[2][4];
#pragma unroll
    for (int i = 0; i < 2; i++)
#pragma unroll
        for (int e = 0; e < 4; e++) sreg[i][e] = 0.f;
    for (int i = tid; i < 2 * 16 * 488; i += 512) ((bf16*)mnl)[i] = __float2bfloat16(0.f);
    for (int i = tid; i < 16 * 488; i += 512) ((bf16*)rml)[i] = __float2bfloat16(0.f);
    __syncthreads();

    // step-invariant addressing (row-major panels, KP stride)
    const bf16* wz0p = WzbT + (size_t)(f0 * 16 + lrow) * KP + quad * 8;
    const bf16* wh0p = WhbT + (size_t)(f0 * 16 + lrow) * KP + quad * 8;
    const bf16* wz1p = WzbT + (size_t)(f1 * 16 + lrow) * KP + quad * 8;
    const bf16* wh1p = WhbT + (size_t)(f1 * 16 + lrow) * KP + quad * 8;
    const bf16* ur0p = UrT  + (size_t)(f0 * 16 + lrow) * KP + quad * 8;
    const bf16* ur1p = UrT  + (size_t)(f1 * 16 + lrow) * KP + quad * 8;
    int nidx[4];
    int xo0[4], xo1[4];
#pragma unroll
    for (int e = 0; e < 4; e++) {
        nidx[e] = (row0 + quad * 4 + e) & 1023;
        xo0[e] = nidx[e] * H + c0;
        xo1[e] = nidx[e] * H + c1;
    }

#pragma unroll 1
    for (int u = 0; u < 23; u++) {
        int cur = u & 1, prev = cur ^ 1;
        int src = fwd ? u : 23 - u;
        const bf16* Xzs = Xz + (size_t)src * 1024 * H;
        const bf16* Xhs = Xh + (size_t)src * 1024 * H;
        f32x4 az[2], ah[2];
#pragma unroll
        for (int i = 0; i < 2; i++) {
            az[i] = (f32x4){0.f, 0.f, 0.f, 0.f};
            ah[i] = (f32x4){0.f, 0.f, 0.f, 0.f};
        }
        bf16 xz_pf[2][4], xh_pf[2][4];
        // ---- k1: z_pre = m_prev@Wzb, h_pre = rm_prev@Whb (own frags) ----
        if (u > 0) {
            const bf16* mrow = &mnl[prev][lrow][quad * 8];
            const bf16* rrow = &rml[lrow][quad * 8];
#pragma unroll
            for (int k = 0; k < 15; k++) {
                short8 sA = ld8(mrow + k * 32);
                short8 rA = ld8(rrow + k * 32);
                az[0] = MFMA16(sA, ld8(wz0p + k * 32), az[0]);
                ah[0] = MFMA16(rA, ld8(wh0p + k * 32), ah[0]);
                if (hasf1) {
                    az[1] = MFMA16(sA, ld8(wz1p + k * 32), az[1]);
                    ah[1] = MFMA16(rA, ld8(wh1p + k * 32), ah[1]);
                }
                if (k == 4) {
#pragma unroll
                    for (int e = 0; e < 4; e++) {
                        xz_pf[0][e] = Xzs[xo0[e]];
                        xh_pf[0][e] = Xhs[xo0[e]];
                        if (c1ok) {
                            xz_pf[1][e] = Xzs[xo1[e]];
                            xh_pf[1][e] = Xhs[xo1[e]];
                        }
                    }
                }
            }
        } else {
#pragma unroll
            for (int e = 0; e < 4; e++) {
                xz_pf[0][e] = Xzs[xo0[e]];
                xh_pf[0][e] = Xhs[xo0[e]];
                if (c1ok) {
                    xz_pf[1][e] = Xzs[xo1[e]];
                    xh_pf[1][e] = Xhs[xo1[e]];
                }
            }
        }
        // ---- k1 epilogue: m_new own cols -> sreg, mnl[cur], hs ----
        bf16* hso = hs + (size_t)(fwd ? u : 23 + u) * SLOT;
#pragma unroll
        for (int i = 0; i < 2; i++) {
            int c = i ? c1 : c0;
            bool ok = i ? c1ok : true;
            if (ok) {
#pragma unroll
                for (int e = 0; e < 4; e++) {
                    float zp = az[i][e] + toF(xz_pf[i][e]);
                    float hp = ah[i][e] + toF(xh_pf[i][e]);
                    float z = sigm_f(zp), mt = tanh_f(hp);
                    float mn = (1.f - z) * sreg[i][e] + z * mt;
                    sreg[i][e] = mn;
                    bf16 mb = __float2bfloat16(mn);
                    mnl[cur][quad * 4 + e][c] = mb;
                    hso[(size_t)nidx[e] * HP + c] = mb;
                }
            }
        }

        if (u < 22) {
            // ---- m exchange: export own cols, flag, import partner cols ----
            __syncthreads();                     // mnl[cur] own cols complete
            for (int i = tid; i < 16 * myU; i += 512) {
                int r = i / myU, j = i - r * myU;
                unsigned v = ((unsigned*)&mnl[cur][r][0])[(myBase >> 1) + j];
                __hip_atomic_store(&mexMeU[r * 128 + j], v,
                                   __ATOMIC_RELAXED, __HIP_MEMORY_SCOPE_AGENT);
            }
            __syncthreads();                     // vmcnt drained: exports done
            if (tid == 0) {
                __hip_atomic_store(&flagM[me], u + 1,
                                   __ATOMIC_RELEASE, __HIP_MEMORY_SCOPE_AGENT);
                while (__hip_atomic_load(&flagM[partner],
                                         __ATOMIC_ACQUIRE, __HIP_MEMORY_SCOPE_AGENT) <= u)
                    __builtin_amdgcn_s_sleep(1);
            }
            __syncthreads();
            for (int i = tid; i < 16 * pU; i += 512) {
                int r = i / pU, j = i - r * pU;
                unsigned v = __hip_atomic_load(&mexPU[r * 128 + j],
                                               __ATOMIC_RELAXED, __HIP_MEMORY_SCOPE_AGENT);
                ((unsigned*)&mnl[cur][r][0])[(pBase >> 1) + j] = v;
            }
            ldsbar();                            // full m_new in mnl[cur]

            // ---- k2: r_pre = m_new@Ur + Xr[dst] (own frags) ----
            int dst = fwd ? (u + 1) : (22 - u);
            const bf16* Xrs = Xr + (size_t)dst * 1024 * H;
            f32x4 ar[2];
#pragma unroll
            for (int i = 0; i < 2; i++) ar[i] = (f32x4){0.f, 0.f, 0.f, 0.f};
            bf16 xr_pf[2][4];
            const bf16* mcur = &mnl[cur][lrow][quad * 8];
#pragma unroll
            for (int k = 0; k < 15; k++) {
                short8 mA = ld8(mcur + k * 32);
                ar[0] = MFMA16(mA, ld8(ur0p + k * 32), ar[0]);
                if (hasf1) ar[1] = MFMA16(mA, ld8(ur1p + k * 32), ar[1]);
                if (k == 4) {
#pragma unroll
                    for (int e = 0; e < 4; e++) {
                        xr_pf[0][e] = Xrs[xo0[e]];
                        if (c1ok) xr_pf[1][e] = Xrs[xo1[e]];
                    }
                }
            }
            // rml own cols (safe: last rml reads were in k1; m-exchange
            // barriers separate them)
#pragma unroll
            for (int i = 0; i < 2; i++) {
                int c = i ? c1 : c0;
                bool ok = i ? c1ok : true;
                if (ok) {
#pragma unroll
                    for (int e = 0; e < 4; e++) {
                        float rp = ar[i][e] + toF(xr_pf[i][e]);
                        float mv = toF(__float2bfloat16(sreg[i][e]));
                        rml[quad * 4 + e][c] = __float2bfloat16(sigm_f(rp) * mv);
                    }
                }
            }
            // ---- rm exchange ----
            __syncthreads();
            for (int i = tid; i < 16 * myU; i += 512) {
                int r = i / myU, j = i - r * myU;
                unsigned v = ((unsigned*)&rml[r][0])[(myBase >> 1) + j];
                __hip_atomic_store(&rexMeU[r * 128 + j], v,
                                   __ATOMIC_RELAXED, __HIP_MEMORY_SCOPE_AGENT);
            }
            __syncthreads();
            if (tid == 0) {
                __hip_atomic_store(&flagR[me], u + 1,
                                   __ATOMIC_RELEASE, __HIP_MEMORY_SCOPE_AGENT);
                while (__hip_atomic_load(&flagR[partner],
                                         __ATOMIC_ACQUIRE, __HIP_MEMORY_SCOPE_AGENT) <= u)
                    __builtin_amdgcn_s_sleep(1);
            }
            __syncthreads();
            for (int i = tid; i < 16 * pU; i += 512) {
                int r = i / pU, j = i - r * pU;
                unsigned v = __hip_atomic_load(&rexPU[r * 128 + j],
                                               __ATOMIC_RELAXED, __HIP_MEMORY_SCOPE_AGENT);
                ((unsigned*)&rml[r][0])[(pBase >> 1) + j] = v;
            }
            ldsbar();                            // full rml before next k1
        }
    }
}

// post_scan: hv_fixup (short8 RMW) + q_root (relu(Qtv) -> qh), fused ranges
__global__ __launch_bounds__(256)
void post_scan(bf16* __restrict__ hs, const float* __restrict__ Qtv,
               bf16* __restrict__ qh) {
    int idx = blockIdx.x * 256 + threadIdx.x;
    if (idx < HVR) {
        const int S8 = SLOT / 8;
        int tl = idx / S8;
        int rem = idx - tl * S8;
        short8* h8 = (short8*)hs;
        size_t a = (size_t)(23 + tl) * S8 + rem;
        size_t b = (size_t)(21 - tl) * S8 + rem;
        short8 va = h8[a], vb = h8[b], vo;
#pragma unroll
        for (int e = 0; e < 8; e++)
            vo[e] = f2bs(bf2f(va[e]) + bf2f(vb[e]));
        h8[a] = vo;
    } else if (idx < QRR) {
        int e = idx - HVR;
        int n = e / H, c = e - n * H;
        qh[(size_t)n * HP + c] = __float2bfloat16(fmaxf(Qtv[e], 0.f));
    }
}

// q_reduce (bf16 logits): wave-per-row online softmax + argmax
__global__ __launch_bounds__(256)
void q_reduce(const bf16* __restrict__ ql, const int* __restrict__ wid,
              float* __restrict__ qred) {
    int wave = threadIdx.x >> 6, lane = threadIdx.x & 63;
    int r = blockIdx.x * 4 + wave;
    int t = r >> 10, n = r & 1023;
    int tgt = wid[n * LW + t];
    const short4v* row4 = (const short4v*)(ql + (size_t)r * V);
    float m = -3.4e38f, s = 0.f; int mi = 0x7fffffff;
#pragma unroll
    for (int k = 0; k < 4; k++) {
        int c4 = lane + 64 * k;
        if (c4 < 195) {
            short4v v4 = row4[c4];
#pragma unroll
            for (int e = 0; e < 4; e++) {
                float v = bf2f(v4[e]);
                if (v > m) { s = s * __expf(m - v) + 1.f; m = v; mi = c4 * 4 + e; }
                else s += __expf(v - m);
            }
        }
    }
#pragma unroll
    for (int off = 1; off < 64; off <<= 1) {
        float m2 = __shfl_xor(m, off);
        float s2 = __shfl_xor(s, off);
        int   i2 = __shfl_xor(mi, off);
        if (m2 > m || (m2 == m && i2 < mi)) {
            s = s2 + s * __expf(m - m2);
            m = m2; mi = i2;
        } else {
            s = s + s2 * __expf(m2 - m);
        }
    }
    __shared__ float lred[4][2];
    if (lane == 0) {
        float lse = m + logf(s);
        lred[wave][0] = lse - toF(ql[(size_t)r * V + tgt]);
        lred[wave][1] = (mi == tgt) ? 1.f : 0.f;
    }
    __syncthreads();
    if (threadIdx.x == 0) {
        qred[blockIdx.x * 2]     = lred[0][0] + lred[1][0] + lred[2][0] + lred[3][0];
        qred[blockIdx.x * 2 + 1] = lred[0][1] + lred[1][1] + lred[2][1] + lred[3][1];
    }
}

__global__ __launch_bounds__(256)
void q_final(const float* __restrict__ qred, float* __restrict__ out) {
    int tid = threadIdx.x;
    float L = 0.f, A = 0.f;
    for (int i = tid; i < QBLK; i += 256) { L += qred[2 * i]; A += qred[2 * i + 1]; }
    __shared__ float s1[256], s2[256];
    s1[tid] = L; s2[tid] = A;
    __syncthreads();
    for (int k = 128; k > 0; k >>= 1) {
        if (tid < k) { s1[tid] += s1[tid + k]; s2[tid] += s2[tid + k]; }
        __syncthreads();
    }
    if (tid == 0) {
        out[0] = s1[0] * (1.f / 1024.f);
        out[2] = s2[0] * (1.f / 24576.f);
    }
}

// p root rows
__global__ __launch_bounds__(256)
void p_root(const bf16* __restrict__ XUa, const float* __restrict__ Ptv,
            const float* __restrict__ Us, float* __restrict__ pl) {
    int n = blockIdx.x;
    int tid = threadIdx.x;
    const bf16* xa = XUa + (size_t)n * H;
    const float* pt = Ptv + (size_t)n * H;
    float s = 0.f;
    for (int c = tid; c < H; c += 256)
        s += fmaxf(toF(xa[c]) + pt[c], 0.f) * Us[c];
    __shared__ float red[256];
    red[tid] = s;
    __syncthreads();
    for (int k = 128; k > 0; k >>= 1) {
        if (tid < k) red[tid] += red[tid + k];
        __syncthreads();
    }
    if (tid == 0) pl[n] = red[0];
}

// BCE loss + accuracy
__global__ __launch_bounds__(256)
void p_final(const float* __restrict__ pl, const float* __restrict__ Us_b,
             float* __restrict__ out) {
    int r = blockIdx.x * 256 + threadIdx.x;
    int tid = threadIdx.x;
    float ub = Us_b[0];
    float loss = 0.f, acc = 0.f;
    if (r < PROWS) {
        float l = pl[r] + ub;
        int tgt = (r < PTGT) ? 1 : 0;
        float x = tgt ? -l : l;
        loss = fmaxf(x, 0.f) + log1pf(expf(-fabsf(x)));
        int pred = (l > 0.f) ? 1 : 0;
        acc = (pred == tgt) ? 1.f : 0.f;
    }
    __shared__ float s1[256], s2[256];
    s1[tid] = loss; s2[tid] = acc;
    __syncthreads();
    for (int k = 128; k > 0; k >>= 1) {
        if (tid < k) { s1[tid] += s1[tid + k]; s2[tid] += s2[tid + k]; }
        __syncthreads();
    }
    if (tid == 0) {
        atomicAdd(&out[1], s1[0] * (1.f / 1024.f));
        atomicAdd(&out[3], s2[0] * (1.f / 48128.f));
    }
}

// ---------------------------------------------------------------------------
extern "C" void kernel_launch(void* const* d_in, const int* in_sizes, int n_in,
                              void* d_out, int out_size, void* d_ws, size_t ws_size,
                              hipStream_t stream) {
    const int*   wid  = (const int*)  d_in[0];
    const float* tv   = (const float*)d_in[1];
    const float* emb  = (const float*)d_in[2];
    const float* W_w  = (const float*)d_in[3];
    const float* W_b  = (const float*)d_in[4];
    const float* U_w  = (const float*)d_in[5];
    const float* U_b  = (const float*)d_in[6];
    const float* Wo_w = (const float*)d_in[7];
    const float* Wo_b = (const float*)d_in[8];
    const float* Us_w = (const float*)d_in[9];
    const float* Us_b = (const float*)d_in[10];
    const float* Wz_w = (const float*)d_in[11];
    const float* Wz_b = (const float*)d_in[12];
    const float* Wr_w = (const float*)d_in[13];
    const float* Ur_w = (const float*)d_in[14];
    const float* Ur_b = (const float*)d_in[15];
    const float* Wh_w = (const float*)d_in[16];
    const float* Wh_b = (const float*)d_in[17];
    float* out = (float*)d_out;

    // ---- workspace layout (~145 MiB) ----
    char* base = (char*)d_ws;
    const size_t XBb = XBSZ * 2;
    bf16*  Xz   = (bf16*)(base);
    bf16*  Xh   = (bf16*)(base + XBb);
    bf16*  Xr   = (bf16*)(base + 2 * XBb);
    bf16*  XUa  = (bf16*)(base + 3 * XBb);
    bf16*  hs   = (bf16*)(base + 4 * XBb);               // 46 slots x 1024 x HP
    bf16*  x_all = hs;                                   // alias (dead before scan)
    char*  p1   = base + 4 * XBb + (size_t)NE * SLOT * 2;
    float* Qtv  = (float*)p1;               p1 += (size_t)1024 * H * 4;
    float* Ptv  = (float*)p1;               p1 += (size_t)1024 * H * 4;
    float* pl   = (float*)p1;               p1 += (size_t)PROWS * 4;
    float* qred = (float*)p1;               p1 += (size_t)QBLK * 2 * 4;
    float* bias4 = (float*)p1;              p1 += (size_t)1856 * 4;
    bf16*  BT   = (bf16*)p1;                             // BTROWS x KP
    bf16* BT4   = BT;
    bf16* WzbT  = BT + (size_t)1856 * KP;
    bf16* WhbT  = WzbT + (size_t)512 * KP;
    bf16* UrT   = WhbT + (size_t)512 * KP;
    bf16* UbT   = UrT  + (size_t)512 * KP;
    bf16* WtopT = UbT  + (size_t)512 * KP;
    bf16* WoT   = WtopT + (size_t)512 * KP;              // 896 rows
    bf16* mex   = BT + (size_t)BTROWS * KP;              // 2 MB exchange (m)
    bf16* rex   = mex + EXB;                             // 2 MB exchange (rm)
    int*  flags = (int*)(rex + EXB);                     // flagM[256] | flagR[256]
    int*  flagM = flags;
    int*  flagR = flags + 256;
    // q-path aliases (used after p path completes):
    bf16*  qh = (bf16*)base;
    bf16*  ql = (bf16*)(base + (size_t)QROWS * HP * 2);

    // ---- fused init + weight prep + gather + tv GEMMs (one launch) ----
    prep_all<<<(PR4 + 255) / 256, 256, 0, stream>>>(
        Wz_b, Wh_b, Ur_b, bias4, out, pl, flags,
        Wz_w, Wh_w, Wr_w, U_w, W_w, Wo_w, Ur_w, BT,
        emb, wid, x_all,
        tv, W_w + 450 * 450, W_b, U_w + 900 * 450, U_b, Qtv, Ptv);

    // ---- fused per-node precompute (one 256-tile GEMM, N=1800) ----
    gemm256_pre<<<(QROWS / 256) * 15, 512, 0, stream>>>(x_all, BT4, Xz, bias4);

    // ---- frag-split full scan: 256 blocks x 512 thr (all CUs active) ----
    scan_split<<<256, 512, 0, stream>>>(hs, WzbT, WhbT, UrT, Xz, Xh, Xr,
                                        mex, rex, flagM, flagR);
    post_scan<<<(QRR + 255) / 256, 256, 0, stream>>>(hs, Qtv, qh);

    // ---- p path ----
    p_root<<<1024, 256, 0, stream>>>(XUa, Ptv, Us_w, pl);
    p_gemm256<<<720, 512, 0, stream>>>(hs, UbT, XUa, Ptv, Us_w, pl);
    p_final<<<PROWS / 256, 256, 0, stream>>>(pl, Us_b, out);

    // ---- q path ----
    gemm256<bf16><<<(NF * 1024 / 256) * 4, 512, 0, stream>>>(hs, HP, WtopT, H, 4,
                                                             qh + (size_t)1024 * HP, HP,
                                                             (const float*)nullptr, Qtv, H, 1, 1);
    gemm256<bf16><<<(QROWS / 256) * 7, 512, 0, stream>>>(qh, HP, WoT, V, 7, ql, V,
                                                         Wo_b, (const float*)nullptr, H, 0, 0);
    q_reduce<<<QBLK, 256, 0, stream>>>(ql, wid, qred);
    q_final<<<1, 256, 0, stream>>>(qred, out);

    (void)in_sizes; (void)n_in; (void)out_size; (void)ws_size;
}

// Round 14
// 948.683 us; speedup vs baseline: 1.2245x; 1.2245x over previous
//
#include <hip/hip_runtime.h>
#include <hip/hip_bf16.h>
#include <math.h>

#define H 450
#define HP 464            // padded A row stride (bf16 elems; 16B-aligned rows)
#define KP 480            // padded K extent: 15 MFMA chunks of 32
#define LAT 56
#define V 780
#define LW 24
#define NE 46
#define NF 23
#define SLOT (1024*HP)
#define SROWS 2048
#define QROWS (24*1024)
#define PROWS (47*1024)
#define PTGT  (23*1024)
#define QBLK 6144
#define XBSZ ((size_t)QROWS * H)      // one X block, elems (H stride — r16 layout)
#define BTROWS 5312                   // packed B^T rows

// prep_all fused ranges
#define PR0 1856                      // bias4 pack (+ out zero in first 4)
#define PR1 (PR0 + PROWS)             // pl zero
#define PR2 (PR1 + BTROWS * KP)       // prep_w
#define PR3 (PR2 + 24 * 1024 * 225)   // gather_x
#define PR4 (PR3 + 2 * 1024 * H)      // tv gemm (Qtv z=0 / Ptv z=1)

// post_scan fused ranges
#define HVR (22 * (SLOT / 8))         // hv_fixup (short8 units)
#define QRR (HVR + 1024 * H)          // q_root

typedef __hip_bfloat16 bf16;
typedef __attribute__((ext_vector_type(8))) short short8;
typedef __attribute__((ext_vector_type(4))) short short4v;
typedef __attribute__((ext_vector_type(4))) float f32x4;

#define MFMA16(a,b,c) __builtin_amdgcn_mfma_f32_16x16x32_bf16(a,b,c,0,0,0)

__device__ __forceinline__ float sigm_f(float x) { return 1.f / (1.f + __expf(-x)); }
__device__ __forceinline__ float tanh_f(float x) { return 2.f / (1.f + __expf(-2.f * x)) - 1.f; }
__device__ __forceinline__ float toF(bf16 x) { return __bfloat162float(x); }
__device__ __forceinline__ float bf2f(short s) {
    unsigned u = ((unsigned)(unsigned short)s) << 16;
    return __uint_as_float(u);
}
__device__ __forceinline__ short f2bs(float f) {
    bf16 t = __float2bfloat16(f);
    return *reinterpret_cast<short*>(&t);
}
__device__ __forceinline__ void stV(float* p, float v) { *p = v; }
__device__ __forceinline__ void stV(bf16* p, float v) { *p = __float2bfloat16(v); }
__device__ __forceinline__ short8 ld8(const bf16* p) { return *reinterpret_cast<const short8*>(p); }

// LDS-only barrier: drains LDS ops for cross-wave visibility but does NOT
// drain vmcnt (in-flight global stores/prefetch stay in flight — only LDS
// data crosses waves in the scan).
__device__ __forceinline__ void ldsbar() {
    asm volatile("s_waitcnt lgkmcnt(0)" ::: "memory");
    __builtin_amdgcn_s_barrier();
    asm volatile("" ::: "memory");
}

// async global->LDS (gemm staging — measured-good)
__device__ __forceinline__ void gl_lds(const bf16* g, bf16* l) {
    __builtin_amdgcn_global_load_lds(
        (const __attribute__((address_space(1))) void*)g,
        (__attribute__((address_space(3))) void*)l, 16, 0, 0);
}

// 128-row-tile XCD swizzle
__device__ __forceinline__ void xcd_decode128(int b, int C, int& row0, int& col0) {
    int rres = b & 7;
    int colt = (b >> 3) % C;
    int g    = b / (8 * C);
    row0 = (rres + 8 * g) * 128;
    col0 = colt * 128;
}

// 256-row-tile XCD swizzle (row-tile count must be a multiple of 8)
__device__ __forceinline__ void xcd_decode256(int b, int C, int& row0, int& col0) {
    int rres = b & 7;
    int colt = (b >> 3) % C;
    int g    = b / (8 * C);
    row0 = (rres + 8 * g) * 256;
    col0 = colt * 128;
}

// generalized bijective XCD swizzle for 256-row tiles (needs nwg % 8 == 0,
// but NOT row-tile-count % 8): XCD k gets contiguous chunk [k*nwg/8, ...)
__device__ __forceinline__ void xcd_decode256g(int b, int nwg, int C,
                                               int& row0, int& col0) {
    int swz = (b & 7) * (nwg >> 3) + (b >> 3);
    row0 = (swz / C) * 256;
    col0 = (swz % C) * 128;
}

// ---------------------------------------------------------------------------
// Fused prep: out-zero + bias4 + pl-zero + B^T weight pack + emb gather +
// tv GEMMs (Qtv/Ptv). All ranges independent; one launch.
// Layout: [BT4 1856 | Wzb 512 | Whb 512 | Ur 512 | Ub 512 | Wtop 512 | Wo 896]
__global__ __launch_bounds__(256)
void prep_all(const float* __restrict__ zb, const float* __restrict__ hb,
              const float* __restrict__ rb, float* __restrict__ bias4,
              float* __restrict__ out, float* __restrict__ pl,
              const float* __restrict__ Wz, const float* __restrict__ Wh,
              const float* __restrict__ Wr, const float* __restrict__ Uw,
              const float* __restrict__ Ww, const float* __restrict__ Wo,
              const float* __restrict__ Ur, bf16* __restrict__ BT,
              const float* __restrict__ emb, const int* __restrict__ wid,
              bf16* __restrict__ x_all,
              const float* __restrict__ tv,
              const float* __restrict__ Wlat, const float* __restrict__ Wbias,
              const float* __restrict__ Ulat, const float* __restrict__ Ubias,
              float* __restrict__ Qtv, float* __restrict__ Ptv) {
    int idx = blockIdx.x * 256 + threadIdx.x;
    if (idx < PR0) {
        if (idx < 4) out[idx] = 0.f;
        float v = 0.f;
        if (idx < 450)       v = zb[idx];
        else if (idx < 900)  v = hb[idx - 450];
        else if (idx < 1350) v = rb[idx - 900];
        bias4[idx] = v;
    } else if (idx < PR1) {
        pl[idx - PR0] = 0.f;
    } else if (idx < PR2) {
        int e = idx - PR1;
        int r = e / KP, k = e - r * KP;
        const float* src; int n; int N = H; int ld = H;
        if (r < 1856) {
            if (r < 450)       { src = Wz; n = r; }
            else if (r < 900)  { src = Wh; n = r - 450; }
            else if (r < 1350) { src = Wr; n = r - 900; }
            else               { src = Uw; n = r - 1350; }
        } else if (r < 2368) { src = Wz + 450 * 450; n = r - 1856; }
        else if (r < 2880)   { src = Wh + 450 * 450; n = r - 2368; }
        else if (r < 3392)   { src = Ur;             n = r - 2880; }
        else if (r < 3904)   { src = Uw + 450 * 450; n = r - 3392; }
        else if (r < 4416)   { src = Ww;             n = r - 3904; }
        else                 { src = Wo; n = r - 4416; N = V; ld = V; }
        float v = (n < N && k < H) ? src[(size_t)k * ld + n] : 0.f;
        BT[e] = __float2bfloat16(v);
    } else if (idx < PR3) {
        int e = idx - PR2;
        int row = e / 225, h2 = e - row * 225;
        int t = row >> 10, n = row & 1023;
        int v = wid[n * LW + t];
        float2 x = ((const float2*)(emb + (size_t)v * H))[h2];
        bf16* dst = x_all + (size_t)row * HP + 2 * h2;
        dst[0] = __float2bfloat16(x.x);
        dst[1] = __float2bfloat16(x.y);
    } else if (idx < PR4) {
        // tv GEMM: z=0 -> Qtv = tv@Wlat + Wbias ; z=1 -> Ptv = tv@Ulat + Ubias
        int e = idx - PR3;
        int z = e / (1024 * H);
        int e2 = e - z * (1024 * H);
        int n = e2 / H, c = e2 - n * H;
        const float* W    = z ? Ulat  : Wlat;
        const float* bias = z ? Ubias : Wbias;
        const float* tvn = tv + n * LAT;
        float a = bias[c];
#pragma unroll 8
        for (int k = 0; k < LAT; k++) a += tvn[k] * W[(size_t)k * H + c];
        (z ? Ptv : Qtv)[(size_t)n * H + c] = a;
    }
}

// ---------------------------------------------------------------------------
// LDS-staged GEMM: 128x128 tile, BK=32, global_load_lds + rotate swizzle
// ---------------------------------------------------------------------------
template<typename TC>
__global__ __launch_bounds__(256)
void gemm128(const bf16* __restrict__ A, int lda,
             const bf16* __restrict__ Bt, int N, int cblk,
             TC* __restrict__ C, int ldc,
             const float* __restrict__ bias,
             const float* __restrict__ addrow, int addld, int relu) {
    __shared__ bf16 As[128 * 32];
    __shared__ bf16 Bs[128 * 32];
    int tid = threadIdx.x;
    int lane = tid & 63, wave = tid >> 6;
    int wx = wave & 1, wy = wave >> 1;
    int lrow = lane & 15, quad = lane >> 4;
    int perm = ((quad + (lrow >> 1)) & 3) * 8;
    int row0, col0;
    xcd_decode128(blockIdx.x, cblk, row0, col0);
    f32x4 acc[4][4] = {};
    for (int k0i = 0; k0i < 15; k0i++) {
        int k0 = k0i * 32;
#pragma unroll
        for (int r = 0; r < 2; r++) {
            int tt = r * 256 + tid;
            int row = tt >> 2, cl = tt & 3;
            int cg = (cl - (row >> 1)) & 3;
            gl_lds(A  + (size_t)(row0 + row) * lda + k0 + cg * 8, As + tt * 8);
            gl_lds(Bt + (size_t)(col0 + row) * KP  + k0 + cg * 8, Bs + tt * 8);
        }
        __syncthreads();
        short8 a[4], b[4];
#pragma unroll
        for (int f = 0; f < 4; f++)
            a[f] = ld8(As + (wy * 64 + f * 16 + lrow) * 32 + perm);
#pragma unroll
        for (int f = 0; f < 4; f++)
            b[f] = ld8(Bs + (wx * 64 + f * 16 + lrow) * 32 + perm);
#pragma unroll
        for (int fi = 0; fi < 4; fi++)
#pragma unroll
            for (int fj = 0; fj < 4; fj++)
                acc[fi][fj] = MFMA16(a[fi], b[fj], acc[fi][fj]);
        __syncthreads();
    }
#pragma unroll
    for (int fi = 0; fi < 4; fi++)
#pragma unroll
        for (int e = 0; e < 4; e++) {
            int r = row0 + wy * 64 + fi * 16 + quad * 4 + e;
#pragma unroll
            for (int fj = 0; fj < 4; fj++) {
                int c = col0 + wx * 64 + fj * 16 + lrow;
                if (c >= N) continue;
                float v = acc[fi][fj][e];
                if (bias) v += bias[c];
                if (addrow) v += addrow[(size_t)(r & 1023) * addld + c];
                if (relu) v = fmaxf(v, 0.f);
                stV(&C[(size_t)r * ldc + c], v);
            }
        }
}

// ---------------------------------------------------------------------------
// 256x128-tile GEMM, 512 threads (8 waves, 4x2). Same per-thread register
// profile as gemm128; 2x A-reuse per staged byte, half the barriers per FLOP.
// gswz=0: plain decode256 (row-tiles % 8 == 0); gswz=1: generalized bijective
// swizzle (only needs gridDim.x % 8 == 0).
// ---------------------------------------------------------------------------
template<typename TC>
__global__ __launch_bounds__(512)
void gemm256(const bf16* __restrict__ A, int lda,
             const bf16* __restrict__ Bt, int N, int cblk,
             TC* __restrict__ C, int ldc,
             const float* __restrict__ bias,
             const float* __restrict__ addrow, int addld, int relu, int gswz) {
    __shared__ bf16 As[256 * 32];
    __shared__ bf16 Bs[128 * 32];
    int tid = threadIdx.x;
    int lane = tid & 63, wave = tid >> 6;       // 8 waves
    int wx = wave & 1, wy = wave >> 1;          // wy in 0..3
    int lrow = lane & 15, quad = lane >> 4;
    int perm = ((quad + (lrow >> 1)) & 3) * 8;
    int row0, col0;
    if (gswz) xcd_decode256g(blockIdx.x, gridDim.x, cblk, row0, col0);
    else      xcd_decode256(blockIdx.x, cblk, row0, col0);
    f32x4 acc[4][4] = {};
    for (int k0i = 0; k0i < 15; k0i++) {
        int k0 = k0i * 32;
#pragma unroll
        for (int r = 0; r < 2; r++) {           // A: 2 rounds of 512 thr
            int tt = r * 512 + tid;
            int row = tt >> 2, cl = tt & 3;
            int cg = (cl - (row >> 1)) & 3;
            gl_lds(A + (size_t)(row0 + row) * lda + k0 + cg * 8, As + tt * 8);
        }
        {                                       // B: 1 round
            int row = tid >> 2, cl = tid & 3;
            int cg = (cl - (row >> 1)) & 3;
            gl_lds(Bt + (size_t)(col0 + row) * KP + k0 + cg * 8, Bs + tid * 8);
        }
        __syncthreads();
        short8 a[4], b[4];
#pragma unroll
        for (int f = 0; f < 4; f++)
            a[f] = ld8(As + (wy * 64 + f * 16 + lrow) * 32 + perm);
#pragma unroll
        for (int f = 0; f < 4; f++)
            b[f] = ld8(Bs + (wx * 64 + f * 16 + lrow) * 32 + perm);
#pragma unroll
        for (int fi = 0; fi < 4; fi++)
#pragma unroll
            for (int fj = 0; fj < 4; fj++)
                acc[fi][fj] = MFMA16(a[fi], b[fj], acc[fi][fj]);
        __syncthreads();
    }
#pragma unroll
    for (int fi = 0; fi < 4; fi++)
#pragma unroll
        for (int e = 0; e < 4; e++) {
            int r = row0 + wy * 64 + fi * 16 + quad * 4 + e;
#pragma unroll
            for (int fj = 0; fj < 4; fj++) {
                int c = col0 + wx * 64 + fj * 16 + lrow;
                if (c >= N) continue;
                float v = acc[fi][fj][e];
                if (bias) v += bias[c];
                if (addrow) v += addrow[(size_t)(r & 1023) * addld + c];
                if (relu) v = fmaxf(v, 0.f);
                stV(&C[(size_t)r * ldc + c], v);
            }
        }
}

// 256-tile fused pre-GEMM: X @ [Wz|Wh|Wr|Ua] (N=1800), demux into 4 X blocks
__global__ __launch_bounds__(512)
void gemm256_pre(const bf16* __restrict__ A,
                 const bf16* __restrict__ Bt,
                 bf16* __restrict__ X0,          // Xz; blocks stride XBSZ
                 const float* __restrict__ bias4) {
    __shared__ bf16 As[256 * 32];
    __shared__ bf16 Bs[128 * 32];
    int tid = threadIdx.x;
    int lane = tid & 63, wave = tid >> 6;
    int wx = wave & 1, wy = wave >> 1;
    int lrow = lane & 15, quad = lane >> 4;
    int perm = ((quad + (lrow >> 1)) & 3) * 8;
    int row0, col0;
    xcd_decode256(blockIdx.x, 15, row0, col0);
    f32x4 acc[4][4] = {};
    for (int k0i = 0; k0i < 15; k0i++) {
        int k0 = k0i * 32;
#pragma unroll
        for (int r = 0; r < 2; r++) {
            int tt = r * 512 + tid;
            int row = tt >> 2, cl = tt & 3;
            int cg = (cl - (row >> 1)) & 3;
            gl_lds(A + (size_t)(row0 + row) * HP + k0 + cg * 8, As + tt * 8);
        }
        {
            int row = tid >> 2, cl = tid & 3;
            int cg = (cl - (row >> 1)) & 3;
            gl_lds(Bt + (size_t)(col0 + row) * KP + k0 + cg * 8, Bs + tid * 8);
        }
        __syncthreads();
        short8 a[4], b[4];
#pragma unroll
        for (int f = 0; f < 4; f++)
            a[f] = ld8(As + (wy * 64 + f * 16 + lrow) * 32 + perm);
#pragma unroll
        for (int f = 0; f < 4; f++)
            b[f] = ld8(Bs + (wx * 64 + f * 16 + lrow) * 32 + perm);
#pragma unroll
        for (int fi = 0; fi < 4; fi++)
#pragma unroll
            for (int fj = 0; fj < 4; fj++)
                acc[fi][fj] = MFMA16(a[fi], b[fj], acc[fi][fj]);
        __syncthreads();
    }
#pragma unroll
    for (int fi = 0; fi < 4; fi++)
#pragma unroll
        for (int e = 0; e < 4; e++) {
            int r = row0 + wy * 64 + fi * 16 + quad * 4 + e;
#pragma unroll
            for (int fj = 0; fj < 4; fj++) {
                int c = col0 + wx * 64 + fj * 16 + lrow;
                if (c >= 1800) continue;
                int mm = c / 450;
                int cc = c - mm * 450;
                float v = acc[fi][fj][e] + bias4[c];
                X0[(size_t)mm * XBSZ + (size_t)r * H + cc] = __float2bfloat16(v);
            }
        }
}

// p GEMM (256-tile): hs @ Ub; epilogue relu(+XUa[dst]+Ptv) dot Us -> atomicAdd
// rows = 46080 -> 180 row-tiles x 4 col-tiles = 720 blocks (720 % 8 == 0:
// generalized bijective swizzle applies even though 180 % 8 != 0).
__global__ __launch_bounds__(512)
void p_gemm256(const bf16* __restrict__ hs, const bf16* __restrict__ UbT,
               const bf16* __restrict__ XUa, const float* __restrict__ Ptv,
               const float* __restrict__ Us, float* __restrict__ pl) {
    __shared__ bf16 As[256 * 32];
    __shared__ bf16 Bs[128 * 32];
    int tid = threadIdx.x;
    int lane = tid & 63, wave = tid >> 6;
    int wx = wave & 1, wy = wave >> 1;
    int lrow = lane & 15, quad = lane >> 4;
    int perm = ((quad + (lrow >> 1)) & 3) * 8;
    int row0, col0;
    xcd_decode256g(blockIdx.x, 720, 4, row0, col0);
    f32x4 acc[4][4] = {};
    for (int k0i = 0; k0i < 15; k0i++) {
        int k0 = k0i * 32;
#pragma unroll
        for (int r = 0; r < 2; r++) {
            int tt = r * 512 + tid;
            int row = tt >> 2, cl = tt & 3;
            int cg = (cl - (row >> 1)) & 3;
            gl_lds(hs + (size_t)(row0 + row) * HP + k0 + cg * 8, As + tt * 8);
        }
        {
            int row = tid >> 2, cl = tid & 3;
            int cg = (cl - (row >> 1)) & 3;
            gl_lds(UbT + (size_t)(col0 + row) * KP + k0 + cg * 8, Bs + tid * 8);
        }
        __syncthreads();
        short8 a[4], b[4];
#pragma unroll
        for (int f = 0; f < 4; f++)
            a[f] = ld8(As + (wy * 64 + f * 16 + lrow) * 32 + perm);
#pragma unroll
        for (int f = 0; f < 4; f++)
            b[f] = ld8(Bs + (wx * 64 + f * 16 + lrow) * 32 + perm);
#pragma unroll
        for (int fi = 0; fi < 4; fi++)
#pragma unroll
            for (int fj = 0; fj < 4; fj++)
                acc[fi][fj] = MFMA16(a[fi], b[fj], acc[fi][fj]);
        __syncthreads();
    }
#pragma unroll
    for (int fi = 0; fi < 4; fi++)
#pragma unroll
        for (int e = 0; e < 4; e++) {
            int r = row0 + wy * 64 + fi * 16 + quad * 4 + e;
            int t = r >> 10, n = r & 1023;
            int dst = (t < 23) ? (t + 1) : (45 - t);
            float part = 0.f;
#pragma unroll
            for (int fj = 0; fj < 4; fj++) {
                int c = col0 + wx * 64 + fj * 16 + lrow;
                if (c < H) {
                    float h = fmaxf(acc[fi][fj][e] + toF(XUa[((size_t)dst * 1024 + n) * H + c])
                                    + Ptv[(size_t)n * H + c], 0.f);
                    part += h * Us[c];
                }
            }
#pragma unroll
            for (int off = 1; off < 16; off <<= 1)
                part += __shfl_xor(part, off);
            if (lrow == 0) atomicAdd(&pl[1024 + r], part);
        }
}

// ---------------------------------------------------------------------------
// Barrier-free full scan, 16 waves/block — the verified r3/r8 configuration
// (553 us, VGPR 56, FETCH 60.8 MB / WRITE 42.7 MB, no spill, L2-clean).
// FROZEN after 8 falsified structural theories (r1-r9, r13):
//  register pipelining x3 (spilled at the 64-arch-VGPR wall), LDS ring x2
//  (barrier jitter / L2 thrash), tiled layout x2 (L2 thrash, FETCH 0.74-1.35
//  GB), advisory pacing (null), frag-split across 256 blocks (exchange
//  latency > halved compute). The scan is serial-dependency-chain bound;
//  this configuration is its empirical floor.
// ---------------------------------------------------------------------------
__global__ void
__attribute__((amdgpu_flat_work_group_size(1024, 1024), amdgpu_waves_per_eu(4, 4)))
scan_full(bf16* __restrict__ hs,
          const bf16* __restrict__ WzbT, const bf16* __restrict__ WhbT,
          const bf16* __restrict__ UrT,
          const bf16* __restrict__ Xz, const bf16* __restrict__ Xh,
          const bf16* __restrict__ Xr) {
    __shared__ bf16 mnl[2][16][488];
    __shared__ bf16 rml[16][488];
    int tid = threadIdx.x;
    int lane = tid & 63, w = tid >> 6;          // w in [0,16)
    int lrow = lane & 15, quad = lane >> 4;
    int row0 = blockIdx.x * 16;
    bool fwd = row0 < 1024;
    int f0 = w, f1 = w + 16;                    // f1 valid iff w < 13
    bool hasf1 = (f1 < 29);
    int c0 = f0 * 16 + lrow;                    // always < 256 < H
    int c1 = f1 * 16 + lrow;
    bool c1ok = hasf1 && (c1 < H);              // per-lane (frag 28 is partial)
    float sreg[2][4];
#pragma unroll
    for (int i = 0; i < 2; i++)
#pragma unroll
        for (int e = 0; e < 4; e++) sreg[i][e] = 0.f;
    for (int i = tid; i < 2 * 16 * 488; i += 1024) ((bf16*)mnl)[i] = __float2bfloat16(0.f);
    for (int i = tid; i < 16 * 488; i += 1024) ((bf16*)rml)[i] = __float2bfloat16(0.f);
    __syncthreads();

    // step-invariant addressing (row-major panels, KP stride)
    const bf16* wz0p = WzbT + (size_t)(f0 * 16 + lrow) * KP + quad * 8;
    const bf16* wh0p = WhbT + (size_t)(f0 * 16 + lrow) * KP + quad * 8;
    const bf16* wz1p = WzbT + (size_t)(f1 * 16 + lrow) * KP + quad * 8;
    const bf16* wh1p = WhbT + (size_t)(f1 * 16 + lrow) * KP + quad * 8;
    const bf16* ur0p = UrT  + (size_t)(f0 * 16 + lrow) * KP + quad * 8;
    const bf16* ur1p = UrT  + (size_t)(f1 * 16 + lrow) * KP + quad * 8;
    int nidx[4];
    int xo0[4], xo1[4];   // step-invariant X element offsets
#pragma unroll
    for (int e = 0; e < 4; e++) {
        nidx[e] = (row0 + quad * 4 + e) & 1023;
        xo0[e] = nidx[e] * H + c0;
        xo1[e] = nidx[e] * H + c1;
    }

#pragma unroll 1
    for (int u = 0; u < 23; u++) {
        int cur = u & 1, prev = cur ^ 1;
        int src = fwd ? u : 23 - u;
        const bf16* Xzs = Xz + (size_t)src * 1024 * H;
        const bf16* Xhs = Xh + (size_t)src * 1024 * H;
        f32x4 az[2], ah[2];
#pragma unroll
        for (int i = 0; i < 2; i++) {
            az[i] = (f32x4){0.f, 0.f, 0.f, 0.f};
            ah[i] = (f32x4){0.f, 0.f, 0.f, 0.f};
        }
        bf16 xz_pf[2][4], xh_pf[2][4];
        // ---- k1: z_pre = m_prev@Wzb, h_pre = rm_prev@Whb ----
        if (u > 0) {
            const bf16* mrow = &mnl[prev][lrow][quad * 8];
            const bf16* rrow = &rml[lrow][quad * 8];
#pragma unroll
            for (int k = 0; k < 15; k++) {
                short8 sA = ld8(mrow + k * 32);
                short8 rA = ld8(rrow + k * 32);
                az[0] = MFMA16(sA, ld8(wz0p + k * 32), az[0]);
                ah[0] = MFMA16(rA, ld8(wh0p + k * 32), ah[0]);
                if (hasf1) {
                    az[1] = MFMA16(sA, ld8(wz1p + k * 32), az[1]);
                    ah[1] = MFMA16(rA, ld8(wh1p + k * 32), ah[1]);
                }
                if (k == 4) {
                    // epilogue X prefetch — hides scattered-load latency under MFMAs
#pragma unroll
                    for (int e = 0; e < 4; e++) {
                        xz_pf[0][e] = Xzs[xo0[e]];
                        xh_pf[0][e] = Xhs[xo0[e]];
                        if (c1ok) {
                            xz_pf[1][e] = Xzs[xo1[e]];
                            xh_pf[1][e] = Xhs[xo1[e]];
                        }
                    }
                }
            }
        } else {
#pragma unroll
            for (int e = 0; e < 4; e++) {
                xz_pf[0][e] = Xzs[xo0[e]];
                xh_pf[0][e] = Xhs[xo0[e]];
                if (c1ok) {
                    xz_pf[1][e] = Xzs[xo1[e]];
                    xh_pf[1][e] = Xhs[xo1[e]];
                }
            }
        }
        bf16* hso = hs + (size_t)(fwd ? u : 23 + u) * SLOT;
#pragma unroll
        for (int i = 0; i < 2; i++) {
            int c = i ? c1 : c0;
            bool ok = i ? c1ok : true;
            if (ok) {
#pragma unroll
                for (int e = 0; e < 4; e++) {
                    float zp = az[i][e] + toF(xz_pf[i][e]);
                    float hp = ah[i][e] + toF(xh_pf[i][e]);
                    float z = sigm_f(zp), mt = tanh_f(hp);
                    float mn = (1.f - z) * sreg[i][e] + z * mt;
                    sreg[i][e] = mn;
                    bf16 mb = __float2bfloat16(mn);
                    mnl[cur][quad * 4 + e][c] = mb;
                    hso[(size_t)nidx[e] * HP + c] = mb;
                }
            }
        }
        ldsbar();   // mnl[cur] complete before k2 reads (LDS-only)

        // ---- k2: r_pre = m_new@Ur + Xr[dst]; rml = sig(r_pre)*m_new ----
        if (u < 22) {
            int dst = fwd ? (u + 1) : (22 - u);
            const bf16* Xrs = Xr + (size_t)dst * 1024 * H;
            f32x4 ar[2];
#pragma unroll
            for (int i = 0; i < 2; i++) ar[i] = (f32x4){0.f, 0.f, 0.f, 0.f};
            bf16 xr_pf[2][4];
            const bf16* mcur = &mnl[cur][lrow][quad * 8];
#pragma unroll
            for (int k = 0; k < 15; k++) {
                short8 mA = ld8(mcur + k * 32);
                ar[0] = MFMA16(mA, ld8(ur0p + k * 32), ar[0]);
                if (hasf1) ar[1] = MFMA16(mA, ld8(ur1p + k * 32), ar[1]);
                if (k == 4) {
#pragma unroll
                    for (int e = 0; e < 4; e++) {
                        xr_pf[0][e] = Xrs[xo0[e]];
                        if (c1ok) xr_pf[1][e] = Xrs[xo1[e]];
                    }
                }
            }
#pragma unroll
            for (int i = 0; i < 2; i++) {
                int c = i ? c1 : c0;
                bool ok = i ? c1ok : true;
                if (ok) {
#pragma unroll
                    for (int e = 0; e < 4; e++) {
                        int rl = quad * 4 + e;
                        float rp = ar[i][e] + toF(xr_pf[i][e]);
                        // mnl[cur][rl][c] == bf16(sreg[i][e]) — reuse register
                        float mv = toF(__float2bfloat16(sreg[i][e]));
                        rml[rl][c] = __float2bfloat16(sigm_f(rp) * mv);
                    }
                }
            }
            ldsbar();  // rml complete before next k1 reads
        }
    }
}

// post_scan: hv_fixup (short8 RMW) + q_root (relu(Qtv) -> qh), fused ranges
__global__ __launch_bounds__(256)
void post_scan(bf16* __restrict__ hs, const float* __restrict__ Qtv,
               bf16* __restrict__ qh) {
    int idx = blockIdx.x * 256 + threadIdx.x;
    if (idx < HVR) {
        const int S8 = SLOT / 8;
        int tl = idx / S8;
        int rem = idx - tl * S8;
        short8* h8 = (short8*)hs;
        size_t a = (size_t)(23 + tl) * S8 + rem;
        size_t b = (size_t)(21 - tl) * S8 + rem;
        short8 va = h8[a], vb = h8[b], vo;
#pragma unroll
        for (int e = 0; e < 8; e++)
            vo[e] = f2bs(bf2f(va[e]) + bf2f(vb[e]));
        h8[a] = vo;
    } else if (idx < QRR) {
        int e = idx - HVR;
        int n = e / H, c = e - n * H;
        qh[(size_t)n * HP + c] = __float2bfloat16(fmaxf(Qtv[e], 0.f));
    }
}

// q_reduce (bf16 logits): wave-per-row online softmax + argmax
__global__ __launch_bounds__(256)
void q_reduce(const bf16* __restrict__ ql, const int* __restrict__ wid,
              float* __restrict__ qred) {
    int wave = threadIdx.x >> 6, lane = threadIdx.x & 63;
    int r = blockIdx.x * 4 + wave;
    int t = r >> 10, n = r & 1023;
    int tgt = wid[n * LW + t];
    const short4v* row4 = (const short4v*)(ql + (size_t)r * V);   // 195 chunks of 4
    float m = -3.4e38f, s = 0.f; int mi = 0x7fffffff;
#pragma unroll
    for (int k = 0; k < 4; k++) {
        int c4 = lane + 64 * k;
        if (c4 < 195) {
            short4v v4 = row4[c4];
#pragma unroll
            for (int e = 0; e < 4; e++) {
                float v = bf2f(v4[e]);
                if (v > m) { s = s * __expf(m - v) + 1.f; m = v; mi = c4 * 4 + e; }
                else s += __expf(v - m);
            }
        }
    }
#pragma unroll
    for (int off = 1; off < 64; off <<= 1) {
        float m2 = __shfl_xor(m, off);
        float s2 = __shfl_xor(s, off);
        int   i2 = __shfl_xor(mi, off);
        if (m2 > m || (m2 == m && i2 < mi)) {
            s = s2 + s * __expf(m - m2);
            m = m2; mi = i2;
        } else {
            s = s + s2 * __expf(m2 - m);
        }
    }
    __shared__ float lred[4][2];
    if (lane == 0) {
        float lse = m + logf(s);
        lred[wave][0] = lse - toF(ql[(size_t)r * V + tgt]);
        lred[wave][1] = (mi == tgt) ? 1.f : 0.f;
    }
    __syncthreads();
    if (threadIdx.x == 0) {
        qred[blockIdx.x * 2]     = lred[0][0] + lred[1][0] + lred[2][0] + lred[3][0];
        qred[blockIdx.x * 2 + 1] = lred[0][1] + lred[1][1] + lred[2][1] + lred[3][1];
    }
}

__global__ __launch_bounds__(256)
void q_final(const float* __restrict__ qred, float* __restrict__ out) {
    int tid = threadIdx.x;
    float L = 0.f, A = 0.f;
    for (int i = tid; i < QBLK; i += 256) { L += qred[2 * i]; A += qred[2 * i + 1]; }
    __shared__ float s1[256], s2[256];
    s1[tid] = L; s2[tid] = A;
    __syncthreads();
    for (int k = 128; k > 0; k >>= 1) {
        if (tid < k) { s1[tid] += s1[tid + k]; s2[tid] += s2[tid + k]; }
        __syncthreads();
    }
    if (tid == 0) {
        out[0] = s1[0] * (1.f / 1024.f);
        out[2] = s2[0] * (1.f / 24576.f);
    }
}

// p root rows: pl[n] = sum_c relu(XUa[0][n][c]+Ptv[n][c])*Us[c]  (plain store)
__global__ __launch_bounds__(256)
void p_root(const bf16* __restrict__ XUa, const float* __restrict__ Ptv,
            const float* __restrict__ Us, float* __restrict__ pl) {
    int n = blockIdx.x;
    int tid = threadIdx.x;
    const bf16* xa = XUa + (size_t)n * H;
    const float* pt = Ptv + (size_t)n * H;
    float s = 0.f;
    for (int c = tid; c < H; c += 256)
        s += fmaxf(toF(xa[c]) + pt[c], 0.f) * Us[c];
    __shared__ float red[256];
    red[tid] = s;
    __syncthreads();
    for (int k = 128; k > 0; k >>= 1) {
        if (tid < k) red[tid] += red[tid + k];
        __syncthreads();
    }
    if (tid == 0) pl[n] = red[0];
}

// BCE loss + accuracy; logit = pl[r] + Us_b[0]; target = (r < 23552)
__global__ __launch_bounds__(256)
void p_final(const float* __restrict__ pl, const float* __restrict__ Us_b,
             float* __restrict__ out) {
    int r = blockIdx.x * 256 + threadIdx.x;
    int tid = threadIdx.x;
    float ub = Us_b[0];
    float loss = 0.f, acc = 0.f;
    if (r < PROWS) {
        float l = pl[r] + ub;
        int tgt = (r < PTGT) ? 1 : 0;
        float x = tgt ? -l : l;
        loss = fmaxf(x, 0.f) + log1pf(expf(-fabsf(x)));
        int pred = (l > 0.f) ? 1 : 0;
        acc = (pred == tgt) ? 1.f : 0.f;
    }
    __shared__ float s1[256], s2[256];
    s1[tid] = loss; s2[tid] = acc;
    __syncthreads();
    for (int k = 128; k > 0; k >>= 1) {
        if (tid < k) { s1[tid] += s1[tid + k]; s2[tid] += s2[tid + k]; }
        __syncthreads();
    }
    if (tid == 0) {
        atomicAdd(&out[1], s1[0] * (1.f / 1024.f));
        atomicAdd(&out[3], s2[0] * (1.f / 48128.f));
    }
}

// ---------------------------------------------------------------------------
extern "C" void kernel_launch(void* const* d_in, const int* in_sizes, int n_in,
                              void* d_out, int out_size, void* d_ws, size_t ws_size,
                              hipStream_t stream) {
    const int*   wid  = (const int*)  d_in[0];
    const float* tv   = (const float*)d_in[1];
    const float* emb  = (const float*)d_in[2];
    const float* W_w  = (const float*)d_in[3];
    const float* W_b  = (const float*)d_in[4];
    const float* U_w  = (const float*)d_in[5];
    const float* U_b  = (const float*)d_in[6];
    const float* Wo_w = (const float*)d_in[7];
    const float* Wo_b = (const float*)d_in[8];
    const float* Us_w = (const float*)d_in[9];
    const float* Us_b = (const float*)d_in[10];
    const float* Wz_w = (const float*)d_in[11];
    const float* Wz_b = (const float*)d_in[12];
    const float* Wr_w = (const float*)d_in[13];
    const float* Ur_w = (const float*)d_in[14];
    const float* Ur_b = (const float*)d_in[15];
    const float* Wh_w = (const float*)d_in[16];
    const float* Wh_b = (const float*)d_in[17];
    float* out = (float*)d_out;

    // ---- workspace layout (~140 MiB, r16 layout) ----
    char* base = (char*)d_ws;
    const size_t XBb = XBSZ * 2;                         // bytes per X block
    bf16*  Xz   = (bf16*)(base);
    bf16*  Xh   = (bf16*)(base + XBb);
    bf16*  Xr   = (bf16*)(base + 2 * XBb);
    bf16*  XUa  = (bf16*)(base + 3 * XBb);
    bf16*  hs   = (bf16*)(base + 4 * XBb);               // 46 slots x 1024 x HP
    bf16*  x_all = hs;                                   // alias (dead before scan)
    char*  p1   = base + 4 * XBb + (size_t)NE * SLOT * 2;
    float* Qtv  = (float*)p1;               p1 += (size_t)1024 * H * 4;
    float* Ptv  = (float*)p1;               p1 += (size_t)1024 * H * 4;
    float* pl   = (float*)p1;               p1 += (size_t)PROWS * 4;
    float* qred = (float*)p1;               p1 += (size_t)QBLK * 2 * 4;
    float* bias4 = (float*)p1;              p1 += (size_t)1856 * 4;
    bf16*  BT   = (bf16*)p1;                             // BTROWS x KP
    bf16* BT4   = BT;
    bf16* WzbT  = BT + (size_t)1856 * KP;
    bf16* WhbT  = WzbT + (size_t)512 * KP;
    bf16* UrT   = WhbT + (size_t)512 * KP;
    bf16* UbT   = UrT  + (size_t)512 * KP;
    bf16* WtopT = UbT  + (size_t)512 * KP;
    bf16* WoT   = WtopT + (size_t)512 * KP;              // 896 rows
    // q-path aliases (used after p path completes):
    bf16*  qh = (bf16*)base;                             // 24576 x HP bf16
    bf16*  ql = (bf16*)(base + (size_t)QROWS * HP * 2);  // 24576 x 780 bf16

    // ---- fused init + weight prep + gather + tv GEMMs (one launch) ----
    prep_all<<<(PR4 + 255) / 256, 256, 0, stream>>>(
        Wz_b, Wh_b, Ur_b, bias4, out, pl,
        Wz_w, Wh_w, Wr_w, U_w, W_w, Wo_w, Ur_w, BT,
        emb, wid, x_all,
        tv, W_w + 450 * 450, W_b, U_w + 900 * 450, U_b, Qtv, Ptv);

    // ---- fused per-node precompute (one 256-tile GEMM, N=1800) ----
    gemm256_pre<<<(QROWS / 256) * 15, 512, 0, stream>>>(x_all, BT4, Xz, bias4);

    // ---- barrier-free full scan: one launch, 128 blocks x 1024 thr ----
    scan_full<<<SROWS / 16, 1024, 0, stream>>>(hs, WzbT, WhbT, UrT, Xz, Xh, Xr);
    post_scan<<<(QRR + 255) / 256, 256, 0, stream>>>(hs, Qtv, qh);

    // ---- p path (before q aliases X blocks / hs) ----
    p_root<<<1024, 256, 0, stream>>>(XUa, Ptv, Us_w, pl);
    p_gemm256<<<720, 512, 0, stream>>>(hs, UbT, XUa, Ptv, Us_w, pl);
    p_final<<<PROWS / 256, 256, 0, stream>>>(pl, Us_b, out);

    // ---- q path (qh over Xz/Xh; ql over Xr/XUa/hs-head) ----
    gemm256<bf16><<<(NF * 1024 / 256) * 4, 512, 0, stream>>>(hs, HP, WtopT, H, 4,
                                                             qh + (size_t)1024 * HP, HP,
                                                             (const float*)nullptr, Qtv, H, 1, 1);
    gemm256<bf16><<<(QROWS / 256) * 7, 512, 0, stream>>>(qh, HP, WoT, V, 7, ql, V,
                                                         Wo_b, (const float*)nullptr, H, 0, 0);
    q_reduce<<<QBLK, 256, 0, stream>>>(ql, wid, qred);
    q_final<<<1, 256, 0, stream>>>(qred, out);

    (void)in_sizes; (void)n_in; (void)out_size; (void)ws_size;
}